// Round 17
// baseline (232.229 us; speedup 1.0000x reference)
//
#include <hip/hip_runtime.h>
#include <stdint.h>

typedef unsigned short u16;
typedef unsigned int   u32;
typedef short s16x8 __attribute__((ext_vector_type(8)));
typedef float f32x4 __attribute__((ext_vector_type(4)));

#define NB    16384   // batch
#define NIN   1024
#define WLY   512
#define NLAY  8
#define NNODE (NIN + NLAY * WLY)   // 5120
#define BN    32      // batch columns per block (512 blocks, 2/CU drifting)

__device__ __forceinline__ u16 f2bf(float f) {
  union { float f; u32 u; } c; c.f = f;
  return (u16)((c.u + 0x7fffu + ((c.u >> 16) & 1u)) >> 16);   // RNE
}
__device__ __forceinline__ float bf2f(u16 h) {
  union { u32 u; float f; } c; c.u = ((u32)h) << 16;
  return c.f;
}

#define SCHED0() __builtin_amdgcn_sched_barrier(0)
#define BAR()    __builtin_amdgcn_s_barrier()
#define WAITLG0() asm volatile("s_waitcnt lgkmcnt(0)" ::: "memory")

// ---------- prep: fragment-major Wfrag (r3..r13-proven) ----------
// chunk = ((l*8 + kt)*32 + mb')*2 + kf ; lane maps: m = mb'*16 + (lane&15),
// k = kt*64 + kf*32 + (lane>>4)*8 + j
__global__ void prep_w(const float* __restrict__ W, const float* __restrict__ Mk,
                       u16* __restrict__ Wm) {
  int id   = blockIdx.x * 256 + threadIdx.x;   // 262144
  int lane = id & 63;
  int chunk = id >> 6;                         // 0..4095
  int kf = chunk & 1;
  int mb = (chunk >> 1) & 31;
  int kt = (chunk >> 6) & 7;
  int l  = chunk >> 9;
  int m  = (mb << 4) + (lane & 15);
  int k0 = (kt << 6) + (kf << 5) + ((lane >> 4) << 3);
  size_t base = ((size_t)l << 18) + (size_t)m * 512 + k0;
  const float4* w4 = (const float4*)(W + base);
  const float4* k4 = (const float4*)(Mk + base);
  float4 w0 = w4[0], w1 = w4[1];
  float4 k0v = k4[0], k1v = k4[1];
  u32 p0 = (u32)f2bf(w0.x * k0v.x) | ((u32)f2bf(w0.y * k0v.y) << 16);
  u32 p1 = (u32)f2bf(w0.z * k0v.z) | ((u32)f2bf(w0.w * k0v.w) << 16);
  u32 p2 = (u32)f2bf(w1.x * k1v.x) | ((u32)f2bf(w1.y * k1v.y) << 16);
  u32 p3 = (u32)f2bf(w1.z * k1v.z) | ((u32)f2bf(w1.w * k1v.w) << 16);
  uint4 v; v.x = p0; v.y = p1; v.z = p2; v.w = p3;
  *(uint4*)(Wm + ((size_t)chunk << 9) + (lane << 3)) = v;
}

// ---------- fused net: 4-wave blocks, 2 independent barrier groups / CU ----
// Block (nslice = bx&255, nhalf = bx>>8): n0 = nslice*64 + nhalf*32.
// Siblings bx, bx+256 share the 64-col line-pair and the same XCD L2
// (256 % 8 == 0 under round-robin) -> no gather over-fetch (r7 lesson).
// All V traffic block-local (own 32 cols only) -> no cross-block deps.
// r13 cadence: 4 phases of K=128, lgkm0+BAR publishes, VMEM flies across.
__global__ __launch_bounds__(256, 2) void fused_net(
    const float* __restrict__ x, const u16* __restrict__ Wfrag,
    const float* __restrict__ bias, const int* __restrict__ in_idx,
    u16* __restrict__ V, float* __restrict__ out) {

  __shared__ __align__(16) u16 Graw[2][64 * 40];  // k-major, 80B rows (10KB)
  __shared__ __align__(16) u16 Gswz[4][2048];     // [32n][128B] swz ring (16KB)
  __shared__ __align__(16) u16 Ebuf[512 * 40];    // epilogue / x-transpose (40KB)

  int t = threadIdx.x;
  int lane = t & 63, w = t >> 6;        // w in [0,4)
  int mlane = lane & 15, g = lane >> 4;
  int n0 = ((blockIdx.x & 255) << 6) + ((blockIdx.x >> 8) << 5);
  int krow = (w << 4) + (lane >> 2);    // staged V-row (own wave: 16w..16w+15)
  int kcol = lane & 3;                  // 8-col (16B) chunk within 32-col row

  // ---- x prologue: V[c][n0..n0+32) = bf16(x[n][c]) for c<1024 ----
  float* xt = (float*)Ebuf;                     // [32 b][128 c] f32 = 16KB
  for (int cc = 0; cc < 8; ++cc) {
    #pragma unroll
    for (int it = 0; it < 4; ++it) {
      int cl = t + it * 256;                    // 0..1023
      int b = cl >> 5, p = cl & 31;
      *(float4*)(xt + b * 128 + (p << 2)) =
          *(const float4*)(x + (size_t)(n0 + b) * 1024 + cc * 128 + (p << 2));
    }
    __syncthreads();
    {
      int c = t >> 1, seg = t & 1;              // c 0..127, seg packs 16 batches
      u32 p[8];
      #pragma unroll
      for (int i = 0; i < 8; ++i) {
        u16 lo = f2bf(xt[(seg * 16 + 2 * i) * 128 + c]);
        u16 hi = f2bf(xt[(seg * 16 + 2 * i + 1) * 128 + c]);
        p[i] = (u32)lo | ((u32)hi << 16);
      }
      u16* dst = V + (size_t)(cc * 128 + c) * NB + n0 + seg * 16;
      uint4 v0; v0.x = p[0]; v0.y = p[1]; v0.z = p[2]; v0.w = p[3];
      uint4 v1; v1.x = p[4]; v1.y = p[5]; v1.z = p[6]; v1.w = p[7];
      *(uint4*)dst = v0;
      *(uint4*)(dst + 8) = v1;
    }
    __syncthreads();
  }

#define GLD(KT) do {                                                           \
    gv[(KT) & 3] =                                                             \
        *(const uint4*)(V + (size_t)rowv[KT] * NB + n0 + (kcol << 3));         \
  } while (0)

#define STW(KT) do {                                                           \
    *(uint4*)((char*)Graw[(KT) & 1] + krow * 80 + (kcol << 4)) = gv[(KT) & 3]; \
  } while (0)

// wave w transposes its own rows 16w..16w+15; lane: n = lane&31, rg = lane>>5
#define TRANSP(KT) do {                                                        \
    const u16* gb_ = Graw[(KT) & 1];                                           \
    int n_ = lane & 31, rg_ = lane >> 5;                                       \
    int rb_ = (w << 4) + (rg_ << 3);                                           \
    u32 p0_ = (u32)gb_[(rb_ + 0) * 40 + n_] |                                  \
              ((u32)gb_[(rb_ + 1) * 40 + n_] << 16);                           \
    u32 p1_ = (u32)gb_[(rb_ + 2) * 40 + n_] |                                  \
              ((u32)gb_[(rb_ + 3) * 40 + n_] << 16);                           \
    u32 p2_ = (u32)gb_[(rb_ + 4) * 40 + n_] |                                  \
              ((u32)gb_[(rb_ + 5) * 40 + n_] << 16);                           \
    u32 p3_ = (u32)gb_[(rb_ + 6) * 40 + n_] |                                  \
              ((u32)gb_[(rb_ + 7) * 40 + n_] << 16);                           \
    uint4 vv_; vv_.x = p0_; vv_.y = p1_; vv_.z = p2_; vv_.w = p3_;             \
    *(uint4*)((char*)Gswz[(KT) & 3] + n_ * 128 +                               \
              (((w << 5) + (rg_ << 4)) ^ ((n_ & 7) << 4))) = vv_;              \
  } while (0)

#define LDA(KTN) do {                                                          \
    _Pragma("unroll") for (int mb = 0; mb < 8; ++mb)                           \
    _Pragma("unroll") for (int kf = 0; kf < 2; ++kf)                           \
      a[mb][kf] = *(const s16x8*)(Wl +                                         \
          ((size_t)((((KTN) * 32 + (w << 3) + mb) << 1) + kf) << 9) +          \
          (lane << 3));                                                        \
  } while (0)

#define MM(KT) do {                                                            \
    const char* gs_ = (const char*)Gswz[(KT) & 3];                             \
    _Pragma("unroll") for (int kf = 0; kf < 2; ++kf) {                         \
      s16x8 bfr[2];                                                            \
      _Pragma("unroll") for (int nf = 0; nf < 2; ++nf) {                       \
        int n_ = (nf << 4) + mlane;                                            \
        bfr[nf] = *(const s16x8*)(gs_ + n_ * 128 +                             \
                  (((kf << 6) + (g << 4)) ^ ((n_ & 7) << 4)));                 \
      }                                                                        \
      _Pragma("unroll") for (int mb = 0; mb < 8; ++mb)                         \
      _Pragma("unroll") for (int nf = 0; nf < 2; ++nf)                         \
        acc[mb][nf] = __builtin_amdgcn_mfma_f32_16x16x32_bf16(                 \
            a[mb][kf], bfr[nf], acc[mb][nf], 0, 0, 0);                         \
    }                                                                          \
  } while (0)

  // ---- layer loop ----
  for (int l = 0; l < NLAY; ++l) {
    __syncthreads();   // drains prior epilogue V stores before gathers

    int rowv[8];
    #pragma unroll
    for (int kt = 0; kt < 8; ++kt)
      rowv[kt] = in_idx[(l << 9) + (kt << 6) + krow];

    const u16* Wl = Wfrag + ((size_t)l << 18);
    int node_out = NIN + l * WLY;

    f32x4 acc[8][2];
    #pragma unroll
    for (int i = 0; i < 8; ++i)
      #pragma unroll
      for (int j = 0; j < 2; ++j)
        acc[i][j] = (f32x4){0.f, 0.f, 0.f, 0.f};

    s16x8 a[8][2];
    uint4 gv[4];

    // prologue: tiles 0,1 staged+transposed; 2,3 in flight
    GLD(0); GLD(1);
    STW(0); STW(1);
    TRANSP(0); TRANSP(1);
    GLD(2); GLD(3);
    SCHED0(); WAITLG0(); BAR(); SCHED0();   // publish Gswz[0,1]; VMEM flies

    int rowvn[8];
    if (l + 1 < NLAY) {
      #pragma unroll
      for (int kt = 0; kt < 8; ++kt)
        rowvn[kt] = in_idx[((l + 1) << 9) + (kt << 6) + krow];
    } else {
      #pragma unroll
      for (int kt = 0; kt < 8; ++kt) rowvn[kt] = 0;
    }

    // phase 0: MM 0,1 | stage 2,3 | gathers 4,5 in flight
    GLD(4); GLD(5);
    LDA(0); MM(0);
    LDA(1); MM(1);
    STW(2); STW(3);
    TRANSP(2); TRANSP(3);
    SCHED0(); WAITLG0(); BAR(); SCHED0();

    // phase 1: MM 2,3 | stage 4,5 | gathers 6,7 in flight
    GLD(6); GLD(7);
    LDA(2); MM(2);
    LDA(3); MM(3);
    STW(4); STW(5);
    TRANSP(4); TRANSP(5);
    SCHED0(); WAITLG0(); BAR(); SCHED0();

    // phase 2: MM 4,5 | stage 6,7
    LDA(4); MM(4);
    LDA(5); MM(5);
    STW(6); STW(7);
    TRANSP(6); TRANSP(7);
    SCHED0(); WAITLG0(); BAR(); SCHED0();

    // phase 3: MM 6,7
    LDA(6); MM(6);
    LDA(7); MM(7);

    #pragma unroll
    for (int kt = 0; kt < 8; ++kt) rowv[kt] = rowvn[kt];

    if (l < NLAY - 1) {
      // wave-private epilogue: bias+relu -> Ebuf[m][40] -> coalesced V write
      #pragma unroll
      for (int mb = 0; mb < 8; ++mb) {
        float4 bv = *(const float4*)(bias + (l << 9) + (w << 7) + (mb << 4) + (g << 2));
        float bvr[4] = {bv.x, bv.y, bv.z, bv.w};
        #pragma unroll
        for (int nf = 0; nf < 2; ++nf)
          #pragma unroll
          for (int r = 0; r < 4; ++r) {
            int m = (w << 7) + (mb << 4) + (g << 2) + r;
            int n = (nf << 4) + mlane;
            Ebuf[m * 40 + n] = f2bf(fmaxf(acc[mb][nf][r] + bvr[r], 0.f));
          }
      }
      #pragma unroll
      for (int it = 0; it < 8; ++it) {
        int row = (w << 7) + (it << 4) + (lane >> 2);
        uint4 vv = *(uint4*)(Ebuf + row * 40 + (kcol << 3));
        *(uint4*)(V + (size_t)(node_out + row) * NB + n0 + (kcol << 3)) = vv;
      }
      // no barrier: Ebuf slab + V rows are wave-private; next layer's
      // top __syncthreads drains stores before gathers read them.
    } else {
      // final layer: Ebuf[m][40] -> f32 out[b][j]
      #pragma unroll
      for (int mb = 0; mb < 8; ++mb) {
        float4 bv = *(const float4*)(bias + (l << 9) + (w << 7) + (mb << 4) + (g << 2));
        float bvr[4] = {bv.x, bv.y, bv.z, bv.w};
        #pragma unroll
        for (int nf = 0; nf < 2; ++nf)
          #pragma unroll
          for (int r = 0; r < 4; ++r) {
            int m = (w << 7) + (mb << 4) + (g << 2) + r;
            int n = (nf << 4) + mlane;
            Ebuf[m * 40 + n] = f2bf(fmaxf(acc[mb][nf][r] + bvr[r], 0.f));
          }
      }
      __syncthreads();
      #pragma unroll
      for (int pn = 0; pn < 8; ++pn)
        #pragma unroll
        for (int h = 0; h < 2; ++h) {
          int n = (t >> 6) + (pn << 2);          // 0..31
          int mbase = ((t & 63) << 2) + (h << 8);
          float4 v;
          v.x = bf2f(Ebuf[(mbase + 0) * 40 + n]);
          v.y = bf2f(Ebuf[(mbase + 1) * 40 + n]);
          v.z = bf2f(Ebuf[(mbase + 2) * 40 + n]);
          v.w = bf2f(Ebuf[(mbase + 3) * 40 + n]);
          *(float4*)(out + (size_t)(n0 + n) * 512 + mbase) = v;
        }
    }
  }
#undef GLD
#undef STW
#undef TRANSP
#undef LDA
#undef MM
}

extern "C" void kernel_launch(void* const* d_in, const int* in_sizes, int n_in,
                              void* d_out, int out_size, void* d_ws, size_t ws_size,
                              hipStream_t stream) {
  (void)in_sizes; (void)n_in; (void)out_size; (void)ws_size;
  const float* x    = (const float*)d_in[0];
  const float* W    = (const float*)d_in[1];
  const float* Mk   = (const float*)d_in[2];
  const float* bias = (const float*)d_in[3];
  const int*  inidx = (const int*)d_in[4];
  float* out = (float*)d_out;

  char* ws = (char*)d_ws;
  u16* V     = (u16*)ws;                                   // 160 MiB
  u16* Wfrag = (u16*)(ws + (size_t)NNODE * NB * 2);        // 4 MiB @ 160 MiB

  prep_w<<<dim3(1024), 256, 0, stream>>>(W, Mk, Wfrag);
  fused_net<<<dim3(512), 256, 0, stream>>>(x, Wfrag, bias, inidx, V, out);
}

// Round 18
// 108.813 us; speedup vs baseline: 2.1342x; 2.1342x over previous
//
#include <hip/hip_runtime.h>
#include <stdint.h>

typedef unsigned short u16;
typedef unsigned int   u32;
typedef short s16x8 __attribute__((ext_vector_type(8)));
typedef float f32x4 __attribute__((ext_vector_type(4)));

#define NB    16384   // batch
#define NIN   1024
#define WLY   512
#define NLAY  8
#define NNODE (NIN + NLAY * WLY)   // 5120
#define BN    64      // batch columns per block

__device__ __forceinline__ u16 f2bf(float f) {
  union { float f; u32 u; } c; c.f = f;
  return (u16)((c.u + 0x7fffu + ((c.u >> 16) & 1u)) >> 16);   // RNE
}
__device__ __forceinline__ float bf2f(u16 h) {
  union { u32 u; float f; } c; c.u = ((u32)h) << 16;
  return c.f;
}

#define SCHED0() __builtin_amdgcn_sched_barrier(0)
#define BAR()    __builtin_amdgcn_s_barrier()
#define WAITLG0() asm volatile("s_waitcnt lgkmcnt(0)" ::: "memory")

// ---------- prep: fragment-major Wfrag (r3..r13-proven) ----------
// chunk = ((l*8 + kt)*32 + mb)*2 + kf ; lane maps: m = mb*16 + (lane&15),
// k = kt*64 + kf*32 + (lane>>4)*8 + j
__global__ void prep_w(const float* __restrict__ W, const float* __restrict__ Mk,
                       u16* __restrict__ Wm) {
  int id   = blockIdx.x * 256 + threadIdx.x;   // 262144
  int lane = id & 63;
  int chunk = id >> 6;                         // 0..4095
  int kf = chunk & 1;
  int mb = (chunk >> 1) & 31;
  int kt = (chunk >> 6) & 7;
  int l  = chunk >> 9;
  int m  = (mb << 4) + (lane & 15);
  int k0 = (kt << 6) + (kf << 5) + ((lane >> 4) << 3);
  size_t base = ((size_t)l << 18) + (size_t)m * 512 + k0;
  const float4* w4 = (const float4*)(W + base);
  const float4* k4 = (const float4*)(Mk + base);
  float4 w0 = w4[0], w1 = w4[1];
  float4 k0v = k4[0], k1v = k4[1];
  u32 p0 = (u32)f2bf(w0.x * k0v.x) | ((u32)f2bf(w0.y * k0v.y) << 16);
  u32 p1 = (u32)f2bf(w0.z * k0v.z) | ((u32)f2bf(w0.w * k0v.w) << 16);
  u32 p2 = (u32)f2bf(w1.x * k1v.x) | ((u32)f2bf(w1.y * k1v.y) << 16);
  u32 p3 = (u32)f2bf(w1.z * k1v.z) | ((u32)f2bf(w1.w * k1v.w) << 16);
  uint4 v; v.x = p0; v.y = p1; v.z = p2; v.w = p3;
  *(uint4*)(Wm + ((size_t)chunk << 9) + (lane << 3)) = v;
}

// ---------- fused 8-layer network, one block per 64-batch slice ----------
// r9 dataflow, K=128 per phase (2 tiles): 5 barriers/layer.
// Phase: {2 GLD, 2 LDA, MM x2 (64 MFMA), 2 STW, 2 TRANSP, lgkm0+bar}.
// Graw write+read are same-phase wave-local; Gswz[4] ring crosses waves
// with a full barrier between write and read. VMEM flies across barriers.
__global__ __launch_bounds__(512, 2) void fused_net(
    const float* __restrict__ x, const u16* __restrict__ Wfrag,
    const float* __restrict__ bias, const int* __restrict__ in_idx,
    u16* __restrict__ V, float* __restrict__ out) {

  __shared__ __align__(16) u16 Graw[2][64 * 72];  // k-major, 144B rows (18KB)
  __shared__ __align__(16) u16 Gswz[4][4096];     // n-major XOR-swz ring (32KB)
  __shared__ __align__(16) u16 Ebuf[512 * 72];    // epilogue / x-transpose

  int t = threadIdx.x;
  int lane = t & 63, w = t >> 6;
  int mlane = lane & 15, g = lane >> 4;
  int n0 = blockIdx.x * BN;
  int krow  = (w << 3) + (lane >> 3);   // staged V-row slot (own wave: 8w..8w+7)
  int kcol8 = lane & 7;                 // 8-elem batch chunk

  // ---- x prologue: V[c][n0..n0+64) = bf16(x[n][c]) for c<1024 (r3-proven) ----
  float* xt = (float*)Ebuf;                     // [64 b][128 c] = 32KB
  for (int cc = 0; cc < 8; ++cc) {
    #pragma unroll
    for (int it = 0; it < 4; ++it) {
      int cl = t + it * 512;                    // 0..2047
      int b = cl >> 5, p = cl & 31;
      *(float4*)(xt + b * 128 + (p << 2)) =
          *(const float4*)(x + (size_t)(n0 + b) * 1024 + cc * 128 + (p << 2));
    }
    __syncthreads();
    {
      int c = t >> 2, seg = t & 3;              // c 0..127, seg 0..3
      u32 p[8];
      #pragma unroll
      for (int i = 0; i < 8; ++i) {
        u16 lo = f2bf(xt[(seg * 16 + 2 * i) * 128 + c]);
        u16 hi = f2bf(xt[(seg * 16 + 2 * i + 1) * 128 + c]);
        p[i] = (u32)lo | ((u32)hi << 16);
      }
      u16* dst = V + (size_t)(cc * 128 + c) * NB + n0 + seg * 16;
      uint4 v0; v0.x = p[0]; v0.y = p[1]; v0.z = p[2]; v0.w = p[3];
      uint4 v1; v1.x = p[4]; v1.y = p[5]; v1.z = p[6]; v1.w = p[7];
      *(uint4*)dst = v0;
      *(uint4*)(dst + 8) = v1;
    }
    __syncthreads();
  }

#define GLD(KT) do {                                                           \
    gv[(KT) & 3] =                                                             \
        *(const uint4*)(V + (size_t)rowv[KT] * NB + n0 + (kcol8 << 3));        \
  } while (0)

#define STW(KT) do {                                                           \
    *(uint4*)((char*)Graw[(KT) & 1] + krow * 144 + (kcol8 << 4)) =             \
        gv[(KT) & 3];                                                          \
  } while (0)

#define TRANSP(KT) do {                                                        \
    const u16* gb_ = Graw[(KT) & 1];                                           \
    u32 p0_ = (u32)gb_[(w * 8 + 0) * 72 + lane] |                              \
              ((u32)gb_[(w * 8 + 1) * 72 + lane] << 16);                       \
    u32 p1_ = (u32)gb_[(w * 8 + 2) * 72 + lane] |                              \
              ((u32)gb_[(w * 8 + 3) * 72 + lane] << 16);                       \
    u32 p2_ = (u32)gb_[(w * 8 + 4) * 72 + lane] |                              \
              ((u32)gb_[(w * 8 + 5) * 72 + lane] << 16);                       \
    u32 p3_ = (u32)gb_[(w * 8 + 6) * 72 + lane] |                              \
              ((u32)gb_[(w * 8 + 7) * 72 + lane] << 16);                       \
    uint4 vv_; vv_.x = p0_; vv_.y = p1_; vv_.z = p2_; vv_.w = p3_;             \
    *(uint4*)((char*)Gswz[(KT) & 3] + lane * 128 +                             \
              ((w * 16) ^ ((lane & 7) << 4))) = vv_;                           \
  } while (0)

#define LDA(KTN) do {                                                          \
    _Pragma("unroll") for (int mb = 0; mb < 4; ++mb)                           \
    _Pragma("unroll") for (int kf = 0; kf < 2; ++kf)                           \
      a[(KTN) & 3][mb][kf] = *(const s16x8*)(Wl +                              \
          ((size_t)((((KTN) * 32 + (w << 2) + mb) << 1) + kf) << 9) +          \
          (lane << 3));                                                        \
  } while (0)

#define MM(KT) do {                                                            \
    const char* gs_ = (const char*)Gswz[(KT) & 3];                             \
    _Pragma("unroll") for (int kf = 0; kf < 2; ++kf) {                         \
      s16x8 bfr[4];                                                            \
      _Pragma("unroll") for (int nf = 0; nf < 4; ++nf) {                       \
        int n_ = (nf << 4) + mlane;                                            \
        bfr[nf] = *(const s16x8*)(gs_ + n_ * 128 +                             \
                  (((kf << 6) + (g << 4)) ^ ((n_ & 7) << 4)));                 \
      }                                                                        \
      _Pragma("unroll") for (int mb = 0; mb < 4; ++mb)                         \
      _Pragma("unroll") for (int nf = 0; nf < 4; ++nf)                         \
        acc[mb][nf] = __builtin_amdgcn_mfma_f32_16x16x32_bf16(                 \
            a[(KT) & 3][mb][kf], bfr[nf], acc[mb][nf], 0, 0, 0);               \
    }                                                                          \
  } while (0)

  // ---- layer loop ----
  for (int l = 0; l < NLAY; ++l) {
    __syncthreads();   // drains prior epilogue V stores before gathers

    int rowv[8];
    #pragma unroll
    for (int kt = 0; kt < 8; ++kt)
      rowv[kt] = in_idx[(l << 9) + (kt << 6) + krow];

    const u16* Wl = Wfrag + ((size_t)l << 18);
    int node_out = NIN + l * WLY;

    f32x4 acc[4][4];
    #pragma unroll
    for (int i = 0; i < 4; ++i)
      #pragma unroll
      for (int j = 0; j < 4; ++j)
        acc[i][j] = (f32x4){0.f, 0.f, 0.f, 0.f};

    s16x8 a[4][4][2];
    uint4 gv[4];

    // layer prologue: tiles 0,1 staged+transposed; tiles 2,3 in flight
    GLD(0); GLD(1);
    LDA(0); LDA(1);
    STW(0); STW(1);
    TRANSP(0); TRANSP(1);
    GLD(2); GLD(3);
    SCHED0(); WAITLG0(); BAR(); SCHED0();   // publish Gswz[0,1]; VMEM flies

    // phase 0: MM tiles 0,1 | stage tiles 2,3 | prefetch 4,5
    GLD(4); GLD(5);
    LDA(2); LDA(3);
    MM(0); MM(1);
    STW(2); STW(3);
    TRANSP(2); TRANSP(3);
    SCHED0(); WAITLG0(); BAR(); SCHED0();

    // phase 1: MM tiles 2,3 | stage tiles 4,5 | prefetch 6,7
    GLD(6); GLD(7);
    LDA(4); LDA(5);
    MM(2); MM(3);
    STW(4); STW(5);
    TRANSP(4); TRANSP(5);
    SCHED0(); WAITLG0(); BAR(); SCHED0();

    // phase 2: MM tiles 4,5 | stage tiles 6,7
    LDA(6); LDA(7);
    MM(4); MM(5);
    STW(6); STW(7);
    TRANSP(6); TRANSP(7);
    SCHED0(); WAITLG0(); BAR(); SCHED0();

    // phase 3: MM tiles 6,7 (no staging)
    MM(6); MM(7);

    if (l < NLAY - 1) {
      // wave-private epilogue: bias+relu -> Ebuf[m][72] -> coalesced V write
      #pragma unroll
      for (int mb = 0; mb < 4; ++mb) {
        float4 bv = *(const float4*)(bias + (l << 9) + (w << 6) + (mb << 4) + (g << 2));
        float bvr[4] = {bv.x, bv.y, bv.z, bv.w};
        #pragma unroll
        for (int nf = 0; nf < 4; ++nf)
          #pragma unroll
          for (int r = 0; r < 4; ++r) {
            int m = (w << 6) + (mb << 4) + (g << 2) + r;
            int n = (nf << 4) + mlane;
            Ebuf[m * 72 + n] = f2bf(fmaxf(acc[mb][nf][r] + bvr[r], 0.f));
          }
      }
      #pragma unroll
      for (int it = 0; it < 8; ++it) {
        int row = (w << 6) + (it << 3) + (lane >> 3);
        uint4 vv = *(uint4*)(Ebuf + row * 72 + ((lane & 7) << 3));
        *(uint4*)(V + (size_t)(node_out + row) * NB + n0 + ((lane & 7) << 3)) = vv;
      }
      // no barrier: Ebuf slab + V rows are wave-private; next layer's
      // top __syncthreads drains stores before gathers read them.
    } else {
      // final layer: stride-66 Ebuf (bank-clean column reads) -> f32 out
      #pragma unroll
      for (int mb = 0; mb < 4; ++mb) {
        float4 bv = *(const float4*)(bias + (l << 9) + (w << 6) + (mb << 4) + (g << 2));
        float bvr[4] = {bv.x, bv.y, bv.z, bv.w};
        #pragma unroll
        for (int nf = 0; nf < 4; ++nf)
          #pragma unroll
          for (int r = 0; r < 4; ++r) {
            int m = (w << 6) + (mb << 4) + (g << 2) + r;
            int n = (nf << 4) + mlane;
            Ebuf[m * 66 + n] = f2bf(fmaxf(acc[mb][nf][r] + bvr[r], 0.f));
          }
      }
      __syncthreads();
      #pragma unroll
      for (int pn = 0; pn < 8; ++pn)
        #pragma unroll
        for (int h = 0; h < 2; ++h) {
          int n = (t >> 6) + (pn << 3);
          int mbase = ((t & 63) << 2) + (h << 8);
          float4 v;
          v.x = bf2f(Ebuf[(mbase + 0) * 66 + n]);
          v.y = bf2f(Ebuf[(mbase + 1) * 66 + n]);
          v.z = bf2f(Ebuf[(mbase + 2) * 66 + n]);
          v.w = bf2f(Ebuf[(mbase + 3) * 66 + n]);
          *(float4*)(out + (size_t)(n0 + n) * 512 + mbase) = v;
        }
    }
  }
#undef GLD
#undef STW
#undef TRANSP
#undef LDA
#undef MM
}

extern "C" void kernel_launch(void* const* d_in, const int* in_sizes, int n_in,
                              void* d_out, int out_size, void* d_ws, size_t ws_size,
                              hipStream_t stream) {
  (void)in_sizes; (void)n_in; (void)out_size; (void)ws_size;
  const float* x    = (const float*)d_in[0];
  const float* W    = (const float*)d_in[1];
  const float* Mk   = (const float*)d_in[2];
  const float* bias = (const float*)d_in[3];
  const int*  inidx = (const int*)d_in[4];
  float* out = (float*)d_out;

  char* ws = (char*)d_ws;
  u16* V     = (u16*)ws;                                   // 160 MiB
  u16* Wfrag = (u16*)(ws + (size_t)NNODE * NB * 2);        // 4 MiB @ 160 MiB

  prep_w<<<dim3(1024), 256, 0, stream>>>(W, Mk, Wfrag);
  fused_net<<<dim3(256), 512, 0, stream>>>(x, Wfrag, bias, inidx, V, out);
}